// Round 1
// baseline (222.669 us; speedup 1.0000x reference)
//
#include <hip/hip_runtime.h>
#include <hip/hip_bf16.h>
#include <math.h>

// Shapes: image (32,3,64,64); conv1 -> y1 (32,24,32,32); conv2 -> y2 (32,24,16,16)
// head: s = sum_hw of [f2, coords] (26 per n); relations (32,128); h (32,1024); out (32,2)

#define N_BATCH 32
#define C1_IN 3
#define C_OUT 24
#define H1 32       // conv1 output spatial
#define H2 16       // conv2 output spatial
#define TOT1 (N_BATCH * C_OUT * H1 * H1)   // 786432
#define TOT2 (N_BATCH * C_OUT * H2 * H2)   // 196608

__global__ __launch_bounds__(256) void conv1_kernel(
    const float* __restrict__ img, const float* __restrict__ w,
    const float* __restrict__ b, float* __restrict__ y) {
  int idx = blockIdx.x * 256 + threadIdx.x;
  if (idx >= TOT1) return;
  int ow = idx & 31;
  int oh = (idx >> 5) & 31;
  int co = (idx >> 10) % C_OUT;
  int n  = idx / (C_OUT * 1024);
  float acc = b[co];
  #pragma unroll
  for (int ci = 0; ci < 3; ci++) {
    const float* ip = img + (n * 3 + ci) * 64 * 64;
    const float* wp = w + (co * 3 + ci) * 9;
    #pragma unroll
    for (int kh = 0; kh < 3; kh++) {
      int ih = oh * 2 - 1 + kh;
      if (ih < 0 || ih >= 64) continue;
      #pragma unroll
      for (int kw = 0; kw < 3; kw++) {
        int iw = ow * 2 - 1 + kw;
        if (iw < 0 || iw >= 64) continue;
        acc += ip[ih * 64 + iw] * wp[kh * 3 + kw];
      }
    }
  }
  y[idx] = acc;
}

// One block per channel: sum & sumsq over N*HW elements, write mu and rstd.
__global__ __launch_bounds__(256) void bnstats_kernel(
    const float* __restrict__ y, float* __restrict__ mr, int C, int HW, int N) {
  int c = blockIdx.x;
  int t = threadIdx.x;
  int M = N * HW;
  float s = 0.f, s2 = 0.f;
  for (int e = t; e < M; e += 256) {
    int n = e / HW, p = e % HW;
    float v = y[(n * C + c) * HW + p];
    s += v;
    s2 += v * v;
  }
  __shared__ float sh[256], sh2[256];
  sh[t] = s; sh2[t] = s2;
  __syncthreads();
  for (int off = 128; off > 0; off >>= 1) {
    if (t < off) { sh[t] += sh[t + off]; sh2[t] += sh2[t + off]; }
    __syncthreads();
  }
  if (t == 0) {
    float mu = sh[0] / (float)M;
    float var = sh2[0] / (float)M - mu * mu;
    mr[c] = mu;
    mr[C + c] = rsqrtf(var + 1e-5f);
  }
}

__global__ __launch_bounds__(256) void bnrelu_kernel(
    float* __restrict__ y, const float* __restrict__ mr,
    const float* __restrict__ g, const float* __restrict__ bt,
    int C, int HW, int total) {
  int idx = blockIdx.x * 256 + threadIdx.x;
  if (idx >= total) return;
  int c = (idx / HW) % C;
  float v = (y[idx] - mr[c]) * mr[C + c] * g[c] + bt[c];
  y[idx] = v > 0.f ? v : 0.f;
}

__global__ __launch_bounds__(256) void conv2_kernel(
    const float* __restrict__ f1, const float* __restrict__ w,
    const float* __restrict__ b, float* __restrict__ y) {
  int idx = blockIdx.x * 256 + threadIdx.x;
  if (idx >= TOT2) return;
  int ow = idx & 15;
  int oh = (idx >> 4) & 15;
  int co = (idx >> 8) % C_OUT;
  int n  = idx / (C_OUT * 256);
  float acc = b[co];
  for (int ci = 0; ci < C_OUT; ci++) {
    const float* ip = f1 + (n * C_OUT + ci) * 1024;
    const float* wp = w + (co * C_OUT + ci) * 9;
    #pragma unroll
    for (int kh = 0; kh < 3; kh++) {
      int ih = oh * 2 - 1 + kh;
      if (ih < 0 || ih >= 32) continue;
      #pragma unroll
      for (int kw = 0; kw < 3; kw++) {
        int iw = ow * 2 - 1 + kw;
        if (iw < 0 || iw >= 32) continue;
        acc += ip[ih * 32 + iw] * wp[kh * 3 + kw];
      }
    }
  }
  y[idx] = acc;
}

// One block per batch element n: full relational head.
__global__ __launch_bounds__(256) void head_kernel(
    const float* __restrict__ f2, const float* __restrict__ ques,
    const float* __restrict__ w_rel, const float* __restrict__ b_rel,
    const float* __restrict__ w_fc1, const float* __restrict__ b_fc1,
    const float* __restrict__ w_fc2, const float* __restrict__ b_fc2,
    float* __restrict__ out) {
  int n = blockIdx.x;
  int t = threadIdx.x;
  __shared__ float s_s[26];
  __shared__ float s_rel[128];
  __shared__ float s_h[1024];
  __shared__ float partial[256];

  // spatial sums: 8 threads per channel
  if (t < 192) {
    int f = t >> 3, l = t & 7;
    const float* p = f2 + (n * C_OUT + f) * 256;
    float a = 0.f;
    for (int hw = l; hw < 256; hw += 8) a += p[hw];
    partial[t] = a;
  }
  __syncthreads();
  if (t < 24) {
    float a = 0.f;
    #pragma unroll
    for (int l = 0; l < 8; l++) a += partial[t * 8 + l];
    s_s[t] = a;
  }
  if (t == 24 || t == 25) {
    // sum of coords over the 256 positions: 16 * sum(linspace(-1,1,16))
    float cs = 0.f;
    for (int i = 0; i < 16; i++) cs += -1.f + 2.f * (float)i / 15.f;
    s_s[t] = 16.f * cs;
  }
  __syncthreads();

  // relations[m] = 256 * sum_d s[d]*(Wi+Wj)[d,m] + 65536*(ques[n]@Wq[:,m] + b_rel[m])
  if (t < 128) {
    float acc = 0.f;
    #pragma unroll
    for (int d = 0; d < 26; d++)
      acc += s_s[d] * (w_rel[d * 128 + t] + w_rel[(26 + d) * 128 + t]);
    float q = b_rel[t];
    const float* qv = ques + n * 128;
    for (int k = 0; k < 128; k++) q += qv[k] * w_rel[(52 + k) * 128 + t];
    s_rel[t] = 256.f * acc + 65536.f * q;
  }
  __syncthreads();

  // h = relu(relations @ w_fc1 + b_fc1), 1024 wide
  for (int c = t; c < 1024; c += 256) {
    float acc = b_fc1[c];
    for (int m = 0; m < 128; m++) acc += s_rel[m] * w_fc1[m * 1024 + c];
    s_h[c] = acc > 0.f ? acc : 0.f;
  }
  __syncthreads();

  // out = h @ w_fc2 + b_fc2  (2 outputs)
  float a0 = 0.f, a1 = 0.f;
  for (int c = t; c < 1024; c += 256) {
    float hv = s_h[c];
    a0 += hv * w_fc2[c * 2 + 0];
    a1 += hv * w_fc2[c * 2 + 1];
  }
  partial[t] = a0;
  __syncthreads();
  for (int off = 128; off > 0; off >>= 1) {
    if (t < off) partial[t] += partial[t + off];
    __syncthreads();
  }
  if (t == 0) out[n * 2 + 0] = partial[0] + b_fc2[0];
  __syncthreads();
  partial[t] = a1;
  __syncthreads();
  for (int off = 128; off > 0; off >>= 1) {
    if (t < off) partial[t] += partial[t + off];
    __syncthreads();
  }
  if (t == 0) out[n * 2 + 1] = partial[0] + b_fc2[1];
}

extern "C" void kernel_launch(void* const* d_in, const int* in_sizes, int n_in,
                              void* d_out, int out_size, void* d_ws, size_t ws_size,
                              hipStream_t stream) {
  const float* image   = (const float*)d_in[0];
  const float* ques    = (const float*)d_in[1];
  const float* conv1_w = (const float*)d_in[2];
  const float* conv1_b = (const float*)d_in[3];
  const float* bn1_g   = (const float*)d_in[4];
  const float* bn1_b   = (const float*)d_in[5];
  const float* conv2_w = (const float*)d_in[6];
  const float* conv2_b = (const float*)d_in[7];
  const float* bn2_g   = (const float*)d_in[8];
  const float* bn2_b   = (const float*)d_in[9];
  const float* w_rel   = (const float*)d_in[10];
  const float* b_rel   = (const float*)d_in[11];
  const float* w_fc1   = (const float*)d_in[12];
  const float* b_fc1   = (const float*)d_in[13];
  const float* w_fc2   = (const float*)d_in[14];
  const float* b_fc2   = (const float*)d_in[15];
  float* out = (float*)d_out;

  float* ws  = (float*)d_ws;
  float* y1  = ws;                 // TOT1 = 786432 floats
  float* y2  = y1 + TOT1;          // TOT2 = 196608 floats
  float* mr1 = y2 + TOT2;          // 48 floats (mu[24], rstd[24])
  float* mr2 = mr1 + 48;           // 48 floats

  conv1_kernel<<<(TOT1 + 255) / 256, 256, 0, stream>>>(image, conv1_w, conv1_b, y1);
  bnstats_kernel<<<C_OUT, 256, 0, stream>>>(y1, mr1, C_OUT, 1024, N_BATCH);
  bnrelu_kernel<<<(TOT1 + 255) / 256, 256, 0, stream>>>(y1, mr1, bn1_g, bn1_b, C_OUT, 1024, TOT1);
  conv2_kernel<<<(TOT2 + 255) / 256, 256, 0, stream>>>(y1, conv2_w, conv2_b, y2);
  bnstats_kernel<<<C_OUT, 256, 0, stream>>>(y2, mr2, C_OUT, 256, N_BATCH);
  bnrelu_kernel<<<(TOT2 + 255) / 256, 256, 0, stream>>>(y2, mr2, bn2_g, bn2_b, C_OUT, 256, TOT2);
  head_kernel<<<N_BATCH, 256, 0, stream>>>(y2, ques, w_rel, b_rel, w_fc1, b_fc1,
                                           w_fc2, b_fc2, out);
}

// Round 2
// 201.604 us; speedup vs baseline: 1.1045x; 1.1045x over previous
//
#include <hip/hip_runtime.h>
#include <hip/hip_bf16.h>
#include <math.h>

// Shapes: image (32,3,64,64); conv1 -> y1 (32,24,32,32); conv2 -> y2 (32,24,16,16)
// BN stats fused into conv kernels via block-reduce + atomicAdd.
// bnrelu1 fused into conv2's input reads; bnrelu2 fused into head's spatial sum.

#define N_BATCH 32
#define C_OUT 24
#define TOT1 (N_BATCH * C_OUT * 32 * 32)   // 786432
#define TOT2 (N_BATCH * C_OUT * 16 * 16)   // 196608

// y = conv(image) + b, raw (no BN). Also accumulate per-channel sum/sumsq.
__global__ __launch_bounds__(256) void conv1_kernel(
    const float* __restrict__ img, const float* __restrict__ w,
    const float* __restrict__ b, float* __restrict__ y,
    float* __restrict__ sums) {
  int idx = blockIdx.x * 256 + threadIdx.x;
  int t = threadIdx.x;
  int ow = idx & 31;
  int oh = (idx >> 5) & 31;
  int co = (idx >> 10) % C_OUT;   // constant within a block (256 | 1024)
  int n  = idx / (C_OUT * 1024);
  float acc = b[co];
  #pragma unroll
  for (int ci = 0; ci < 3; ci++) {
    const float* ip = img + (n * 3 + ci) * 64 * 64;
    const float* wp = w + (co * 3 + ci) * 9;
    #pragma unroll
    for (int kh = 0; kh < 3; kh++) {
      int ih = oh * 2 - 1 + kh;
      if (ih < 0 || ih >= 64) continue;
      #pragma unroll
      for (int kw = 0; kw < 3; kw++) {
        int iw = ow * 2 - 1 + kw;
        if (iw < 0 || iw >= 64) continue;
        acc += ip[ih * 64 + iw] * wp[kh * 3 + kw];
      }
    }
  }
  y[idx] = acc;
  // block-level stats reduction (all threads share co)
  __shared__ float sh[256], sh2[256];
  sh[t] = acc; sh2[t] = acc * acc;
  __syncthreads();
  for (int off = 128; off > 0; off >>= 1) {
    if (t < off) { sh[t] += sh[t + off]; sh2[t] += sh2[t + off]; }
    __syncthreads();
  }
  if (t == 0) {
    atomicAdd(&sums[co], sh[0]);
    atomicAdd(&sums[C_OUT + co], sh2[0]);
  }
}

// sums -> per-channel (scale, shift):  bn(x) = x*a + b2
__global__ __launch_bounds__(64) void fin_kernel(
    const float* __restrict__ sums, const float* __restrict__ g,
    const float* __restrict__ bt, float* __restrict__ sc, float invM) {
  int c = threadIdx.x;
  if (c < C_OUT) {
    float mu = sums[c] * invM;
    float var = sums[C_OUT + c] * invM - mu * mu;
    float a = rsqrtf(var + 1e-5f) * g[c];
    sc[c] = a;
    sc[C_OUT + c] = bt[c] - mu * a;
  }
}

// reads raw y1, applies BN1+ReLU inline, conv -> raw y2, accumulates stats2.
__global__ __launch_bounds__(256) void conv2_kernel(
    const float* __restrict__ y1, const float* __restrict__ sc1,
    const float* __restrict__ w, const float* __restrict__ b,
    float* __restrict__ y2, float* __restrict__ sums) {
  int idx = blockIdx.x * 256 + threadIdx.x;
  int t = threadIdx.x;
  int ow = idx & 15;
  int oh = (idx >> 4) & 15;
  int co = (idx >> 8) % C_OUT;    // one full (n,co) plane per block
  int n  = idx / (C_OUT * 256);
  float acc = b[co];
  for (int ci = 0; ci < C_OUT; ci++) {
    const float* ip = y1 + (n * C_OUT + ci) * 1024;
    const float* wp = w + (co * C_OUT + ci) * 9;
    float a1 = sc1[ci], b1 = sc1[C_OUT + ci];
    #pragma unroll
    for (int kh = 0; kh < 3; kh++) {
      int ih = oh * 2 - 1 + kh;
      if (ih < 0 || ih >= 32) continue;
      #pragma unroll
      for (int kw = 0; kw < 3; kw++) {
        int iw = ow * 2 - 1 + kw;
        if (iw < 0 || iw >= 32) continue;
        float v = ip[ih * 32 + iw] * a1 + b1;
        v = v > 0.f ? v : 0.f;
        acc += v * wp[kh * 3 + kw];
      }
    }
  }
  y2[idx] = acc;
  __shared__ float sh[256], sh2[256];
  sh[t] = acc; sh2[t] = acc * acc;
  __syncthreads();
  for (int off = 128; off > 0; off >>= 1) {
    if (t < off) { sh[t] += sh[t + off]; sh2[t] += sh2[t + off]; }
    __syncthreads();
  }
  if (t == 0) {
    atomicAdd(&sums[co], sh[0]);
    atomicAdd(&sums[C_OUT + co], sh2[0]);
  }
}

// One block per batch element n: BN2+ReLU inline, then full relational head.
__global__ __launch_bounds__(256) void head_kernel(
    const float* __restrict__ y2, const float* __restrict__ sc2,
    const float* __restrict__ ques,
    const float* __restrict__ w_rel, const float* __restrict__ b_rel,
    const float* __restrict__ w_fc1, const float* __restrict__ b_fc1,
    const float* __restrict__ w_fc2, const float* __restrict__ b_fc2,
    float* __restrict__ out) {
  int n = blockIdx.x;
  int t = threadIdx.x;
  __shared__ float s_s[26];
  __shared__ float s_rel[128];
  __shared__ float s_h[1024];
  __shared__ float partial[256];

  // spatial sums of relu(bn(y2)): 8 threads per channel
  if (t < 192) {
    int f = t >> 3, l = t & 7;
    const float* p = y2 + (n * C_OUT + f) * 256;
    float a2 = sc2[f], b2 = sc2[C_OUT + f];
    float a = 0.f;
    for (int hw = l; hw < 256; hw += 8) {
      float v = p[hw] * a2 + b2;
      a += (v > 0.f ? v : 0.f);
    }
    partial[t] = a;
  }
  __syncthreads();
  if (t < 24) {
    float a = 0.f;
    #pragma unroll
    for (int l = 0; l < 8; l++) a += partial[t * 8 + l];
    s_s[t] = a;
  }
  if (t == 24 || t == 25) {
    float cs = 0.f;
    for (int i = 0; i < 16; i++) cs += -1.f + 2.f * (float)i / 15.f;
    s_s[t] = 16.f * cs;
  }
  __syncthreads();

  // relations[m] = 256 * s@(Wi+Wj)[:,m] + 65536*(ques[n]@Wq[:,m] + b_rel[m])
  if (t < 128) {
    float acc = 0.f;
    #pragma unroll
    for (int d = 0; d < 26; d++)
      acc += s_s[d] * (w_rel[d * 128 + t] + w_rel[(26 + d) * 128 + t]);
    float q = b_rel[t];
    const float* qv = ques + n * 128;
    for (int k = 0; k < 128; k++) q += qv[k] * w_rel[(52 + k) * 128 + t];
    s_rel[t] = 256.f * acc + 65536.f * q;
  }
  __syncthreads();

  for (int c = t; c < 1024; c += 256) {
    float acc = b_fc1[c];
    for (int m = 0; m < 128; m++) acc += s_rel[m] * w_fc1[m * 1024 + c];
    s_h[c] = acc > 0.f ? acc : 0.f;
  }
  __syncthreads();

  float a0 = 0.f, a1 = 0.f;
  for (int c = t; c < 1024; c += 256) {
    float hv = s_h[c];
    a0 += hv * w_fc2[c * 2 + 0];
    a1 += hv * w_fc2[c * 2 + 1];
  }
  partial[t] = a0;
  __syncthreads();
  for (int off = 128; off > 0; off >>= 1) {
    if (t < off) partial[t] += partial[t + off];
    __syncthreads();
  }
  if (t == 0) out[n * 2 + 0] = partial[0] + b_fc2[0];
  __syncthreads();
  partial[t] = a1;
  __syncthreads();
  for (int off = 128; off > 0; off >>= 1) {
    if (t < off) partial[t] += partial[t + off];
    __syncthreads();
  }
  if (t == 0) out[n * 2 + 1] = partial[0] + b_fc2[1];
}

extern "C" void kernel_launch(void* const* d_in, const int* in_sizes, int n_in,
                              void* d_out, int out_size, void* d_ws, size_t ws_size,
                              hipStream_t stream) {
  const float* image   = (const float*)d_in[0];
  const float* ques    = (const float*)d_in[1];
  const float* conv1_w = (const float*)d_in[2];
  const float* conv1_b = (const float*)d_in[3];
  const float* bn1_g   = (const float*)d_in[4];
  const float* bn1_b   = (const float*)d_in[5];
  const float* conv2_w = (const float*)d_in[6];
  const float* conv2_b = (const float*)d_in[7];
  const float* bn2_g   = (const float*)d_in[8];
  const float* bn2_b   = (const float*)d_in[9];
  const float* w_rel   = (const float*)d_in[10];
  const float* b_rel   = (const float*)d_in[11];
  const float* w_fc1   = (const float*)d_in[12];
  const float* b_fc1   = (const float*)d_in[13];
  const float* w_fc2   = (const float*)d_in[14];
  const float* b_fc2   = (const float*)d_in[15];
  float* out = (float*)d_out;

  float* ws    = (float*)d_ws;
  float* sums1 = ws;            // 48
  float* sums2 = ws + 48;       // 48
  float* sc1   = ws + 96;       // 48
  float* sc2   = ws + 144;      // 48
  float* y1    = ws + 192;      // TOT1
  float* y2    = y1 + TOT1;     // TOT2

  hipMemsetAsync(sums1, 0, 96 * sizeof(float), stream);
  conv1_kernel<<<TOT1 / 256, 256, 0, stream>>>(image, conv1_w, conv1_b, y1, sums1);
  fin_kernel<<<1, 64, 0, stream>>>(sums1, bn1_g, bn1_b, sc1, 1.f / (N_BATCH * 1024));
  conv2_kernel<<<TOT2 / 256, 256, 0, stream>>>(y1, sc1, conv2_w, conv2_b, y2, sums2);
  fin_kernel<<<1, 64, 0, stream>>>(sums2, bn2_g, bn2_b, sc2, 1.f / (N_BATCH * 256));
  head_kernel<<<N_BATCH, 256, 0, stream>>>(y2, sc2, ques, w_rel, b_rel,
                                           w_fc1, b_fc1, w_fc2, b_fc2, out);
}

// Round 3
// 149.264 us; speedup vs baseline: 1.4918x; 1.3507x over previous
//
#include <hip/hip_runtime.h>
#include <hip/hip_bf16.h>
#include <math.h>

// 3-dispatch pipeline:
//  K1 conv1: (n,co) plane per block -> y1 raw + partial sums (no atomics)
//  K2 conv2: folds BN1 finalize per-block, BN1+ReLU inline on reads -> y2 raw + partials
//  K3 head : folds BN2 finalize, spatial sum + relations + fc1 + fc2

#define N_BATCH 32
#define C_OUT 24
#define NB1 (N_BATCH * C_OUT)     // 768 blocks
#define TOT1 (NB1 * 1024)         // 786432
#define TOT2 (NB1 * 256)          // 196608

// partials layout: p[co*32 + n] = sum, p[768 + co*32 + n] = sumsq

__global__ __launch_bounds__(256) void conv1_kernel(
    const float* __restrict__ img, const float* __restrict__ w,
    const float* __restrict__ b, float* __restrict__ y1,
    float* __restrict__ p1) {
  int bid = blockIdx.x;           // n*24 + co
  int t = threadIdx.x;
  int co = bid % C_OUT;
  int n  = bid / C_OUT;
  const float* wbase = w + co * 27;
  float bias = b[co];
  float s = 0.f, s2 = 0.f;
  float* yp = y1 + bid * 1024;
  #pragma unroll
  for (int k = 0; k < 4; k++) {
    int p = t + k * 256;
    int oh = p >> 5, ow = p & 31;
    float acc = bias;
    #pragma unroll
    for (int ci = 0; ci < 3; ci++) {
      const float* ip = img + (n * 3 + ci) * 4096;
      const float* wp = wbase + ci * 9;
      #pragma unroll
      for (int kh = 0; kh < 3; kh++) {
        int ih = oh * 2 - 1 + kh;
        if (ih < 0) continue;
        #pragma unroll
        for (int kw = 0; kw < 3; kw++) {
          int iw = ow * 2 - 1 + kw;
          if (iw < 0) continue;
          acc += ip[ih * 64 + iw] * wp[kh * 3 + kw];
        }
      }
    }
    yp[p] = acc;
    s += acc;
    s2 += acc * acc;
  }
  __shared__ float sh[256], sh2[256];
  sh[t] = s; sh2[t] = s2;
  __syncthreads();
  for (int off = 128; off > 0; off >>= 1) {
    if (t < off) { sh[t] += sh[t + off]; sh2[t] += sh2[t + off]; }
    __syncthreads();
  }
  if (t == 0) {
    p1[co * 32 + n] = sh[0];
    p1[NB1 + co * 32 + n] = sh2[0];
  }
}

__global__ __launch_bounds__(256) void conv2_kernel(
    const float* __restrict__ y1, const float* __restrict__ p1,
    const float* __restrict__ g, const float* __restrict__ bt,
    const float* __restrict__ w, const float* __restrict__ b,
    float* __restrict__ y2, float* __restrict__ p2) {
  int bid = blockIdx.x;           // n*24 + co
  int t = threadIdx.x;
  int co = bid % C_OUT;
  int n  = bid / C_OUT;

  // fold: finalize BN1 scale/shift from partials (all blocks redundantly)
  __shared__ float s_a[C_OUT], s_b[C_OUT];
  if (t < C_OUT) {
    float s = 0.f, s2 = 0.f;
    #pragma unroll 4
    for (int j = 0; j < 32; j++) {
      s += p1[t * 32 + j];
      s2 += p1[NB1 + t * 32 + j];
    }
    float mu = s * (1.f / 32768.f);
    float var = s2 * (1.f / 32768.f) - mu * mu;
    float a = rsqrtf(var + 1e-5f) * g[t];
    s_a[t] = a;
    s_b[t] = bt[t] - mu * a;
  }
  __syncthreads();

  int oh = t >> 4, ow = t & 15;
  float acc = b[co];
  const float* wbase = w + co * (C_OUT * 9);
  for (int ci = 0; ci < C_OUT; ci++) {
    const float* ip = y1 + (n * C_OUT + ci) * 1024;
    const float* wp = wbase + ci * 9;
    float a1 = s_a[ci], b1 = s_b[ci];
    #pragma unroll
    for (int kh = 0; kh < 3; kh++) {
      int ih = oh * 2 - 1 + kh;
      if (ih < 0) continue;
      #pragma unroll
      for (int kw = 0; kw < 3; kw++) {
        int iw = ow * 2 - 1 + kw;
        if (iw < 0) continue;
        float v = ip[ih * 32 + iw] * a1 + b1;
        v = v > 0.f ? v : 0.f;
        acc += v * wp[kh * 3 + kw];
      }
    }
  }
  y2[bid * 256 + t] = acc;

  __shared__ float sh[256], sh2[256];
  sh[t] = acc; sh2[t] = acc * acc;
  __syncthreads();
  for (int off = 128; off > 0; off >>= 1) {
    if (t < off) { sh[t] += sh[t + off]; sh2[t] += sh2[t + off]; }
    __syncthreads();
  }
  if (t == 0) {
    p2[co * 32 + n] = sh[0];
    p2[NB1 + co * 32 + n] = sh2[0];
  }
}

__global__ __launch_bounds__(1024) void head_kernel(
    const float* __restrict__ y2, const float* __restrict__ p2,
    const float* __restrict__ g, const float* __restrict__ bt,
    const float* __restrict__ ques,
    const float* __restrict__ w_rel, const float* __restrict__ b_rel,
    const float* __restrict__ w_fc1, const float* __restrict__ b_fc1,
    const float* __restrict__ w_fc2, const float* __restrict__ b_fc2,
    float* __restrict__ out) {
  int n = blockIdx.x;
  int t = threadIdx.x;
  __shared__ float s_a[C_OUT], s_b[C_OUT];
  __shared__ float s_s[26];
  __shared__ float s_rel[128];
  __shared__ float s_h[1024];
  __shared__ float partial[768];
  __shared__ float s_r0[16], s_r1[16];

  // fold: finalize BN2 from partials
  if (t < C_OUT) {
    float s = 0.f, s2 = 0.f;
    #pragma unroll 4
    for (int j = 0; j < 32; j++) {
      s += p2[t * 32 + j];
      s2 += p2[NB1 + t * 32 + j];
    }
    float mu = s * (1.f / 8192.f);
    float var = s2 * (1.f / 8192.f) - mu * mu;
    float a = rsqrtf(var + 1e-5f) * g[t];
    s_a[t] = a;
    s_b[t] = bt[t] - mu * a;
  }
  __syncthreads();

  // spatial sums of relu(bn(y2)): 32 lanes per channel
  if (t < 768) {
    int ch = t >> 5, l = t & 31;
    const float* p = y2 + (n * C_OUT + ch) * 256;
    float a2 = s_a[ch], b2 = s_b[ch];
    float a = 0.f;
    #pragma unroll
    for (int j = 0; j < 8; j++) {
      float v = p[l + 32 * j] * a2 + b2;
      a += (v > 0.f ? v : 0.f);
    }
    partial[t] = a;
  }
  __syncthreads();
  if (t < 24) {
    float a = 0.f;
    #pragma unroll
    for (int l = 0; l < 32; l++) a += partial[t * 32 + l];
    s_s[t] = a;
  }
  if (t == 24 || t == 25) {
    float cs = 0.f;
    for (int i = 0; i < 16; i++) cs += -1.f + 2.f * (float)i / 15.f;
    s_s[t] = 16.f * cs;
  }
  __syncthreads();

  // relations[m] = 256 * s@(Wi+Wj)[:,m] + 65536*(ques[n]@Wq[:,m] + b_rel[m])
  if (t < 128) {
    float acc = 0.f;
    #pragma unroll
    for (int d = 0; d < 26; d++)
      acc += s_s[d] * (w_rel[d * 128 + t] + w_rel[(26 + d) * 128 + t]);
    float q = b_rel[t];
    const float* qv = ques + n * 128;
    for (int k = 0; k < 128; k++) q += qv[k] * w_rel[(52 + k) * 128 + t];
    s_rel[t] = 256.f * acc + 65536.f * q;
  }
  __syncthreads();

  // fc1: one output per thread
  {
    float acc = b_fc1[t];
    #pragma unroll 8
    for (int m = 0; m < 128; m++) acc += s_rel[m] * w_fc1[m * 1024 + t];
    s_h[t] = acc > 0.f ? acc : 0.f;
  }
  __syncthreads();

  // fc2: 2 outputs, wave shuffle reduce then LDS combine
  {
    float hv = s_h[t];
    float a0 = hv * w_fc2[t * 2 + 0];
    float a1 = hv * w_fc2[t * 2 + 1];
    #pragma unroll
    for (int off = 32; off > 0; off >>= 1) {
      a0 += __shfl_down(a0, off, 64);
      a1 += __shfl_down(a1, off, 64);
    }
    int lane = t & 63, wid = t >> 6;
    if (lane == 0) { s_r0[wid] = a0; s_r1[wid] = a1; }
  }
  __syncthreads();
  if (t == 0) {
    float a0 = 0.f, a1 = 0.f;
    #pragma unroll
    for (int i = 0; i < 16; i++) { a0 += s_r0[i]; a1 += s_r1[i]; }
    out[n * 2 + 0] = a0 + b_fc2[0];
    out[n * 2 + 1] = a1 + b_fc2[1];
  }
}

extern "C" void kernel_launch(void* const* d_in, const int* in_sizes, int n_in,
                              void* d_out, int out_size, void* d_ws, size_t ws_size,
                              hipStream_t stream) {
  const float* image   = (const float*)d_in[0];
  const float* ques    = (const float*)d_in[1];
  const float* conv1_w = (const float*)d_in[2];
  const float* conv1_b = (const float*)d_in[3];
  const float* bn1_g   = (const float*)d_in[4];
  const float* bn1_b   = (const float*)d_in[5];
  const float* conv2_w = (const float*)d_in[6];
  const float* conv2_b = (const float*)d_in[7];
  const float* bn2_g   = (const float*)d_in[8];
  const float* bn2_b   = (const float*)d_in[9];
  const float* w_rel   = (const float*)d_in[10];
  const float* b_rel   = (const float*)d_in[11];
  const float* w_fc1   = (const float*)d_in[12];
  const float* b_fc1   = (const float*)d_in[13];
  const float* w_fc2   = (const float*)d_in[14];
  const float* b_fc2   = (const float*)d_in[15];
  float* out = (float*)d_out;

  float* ws = (float*)d_ws;
  float* p1 = ws;                  // 1536
  float* p2 = ws + 1536;           // 1536
  float* y1 = ws + 3072;           // TOT1
  float* y2 = y1 + TOT1;           // TOT2

  conv1_kernel<<<NB1, 256, 0, stream>>>(image, conv1_w, conv1_b, y1, p1);
  conv2_kernel<<<NB1, 256, 0, stream>>>(y1, p1, bn1_g, bn1_b, conv2_w, conv2_b, y2, p2);
  head_kernel<<<N_BATCH, 1024, 0, stream>>>(y2, p2, bn2_g, bn2_b, ques, w_rel, b_rel,
                                            w_fc1, b_fc1, w_fc2, b_fc2, out);
}